// Round 6
// baseline (107.185 us; speedup 1.0000x reference)
//
#include <hip/hip_runtime.h>
#include <math.h>

// B=1024, D=128, H=128
#define Bn 1024
#define Dn 128
#define Hn 128

// Single fused kernel: 256 blocks x 1024 threads (16 waves/CU, 1 block/CU).
// v7 = v1 (the 94.55us best: phase 1, B1, reduce+stage, tau, LN verbatim)
// with ONLY windows 4a/4b widened from 256 to 1024 threads: thread t handles
// output out=t>>1 (r=out>>7, h=out&127) and k-half half=t&1; partials combine
// via shfl_xor(.,1) within the wave; even lane writes. Per-thread MACs halve,
// active waves 4->16. (History: pre-B1 edits regress — v4 scratch-spill,
// v5 codegen perturbation; post-B1 edits proven safe by v6.)
__global__ __launch_bounds__(1024) void fused_resd1(
    const float* __restrict__ x,
    const float* __restrict__ Wd, const float* __restrict__ bd,
    const float* __restrict__ Wt, const float* __restrict__ bt,
    const float* __restrict__ Wa, const float* __restrict__ ba,
    const float* __restrict__ Wr, const float* __restrict__ br,
    const float* __restrict__ gamma, const float* __restrict__ beta,
    float* __restrict__ out) {
  const int t = threadIdx.x;
  const int c = t & 31;   // column quad: cols 4c..4c+3
  const int g = t >> 5;   // j-group in [0,32)
  const int i0 = blockIdx.x << 2;

  __shared__ float red[32][4][Dn];  // 64 KB: per-group partial column sums
  __shared__ float xs[4][Dn];
  __shared__ float dms[4][Dn];
  __shared__ float ms[4][Hn];
  __shared__ float ys[4][Hn];
  __shared__ float wt_s[Dn];
  __shared__ float tau_s[4];        // 1/tau

  // ---- Phase 1: all-pairs partial sums, 8 loads in flight (verbatim v1) ----
  float4 xi[4];
#pragma unroll
  for (int r = 0; r < 4; ++r)
    xi[r] = *(const float4*)(x + (size_t)(i0 + r) * Dn + c * 4);

  float4 acc[4];
#pragma unroll
  for (int r = 0; r < 4; ++r) acc[r] = make_float4(0.f, 0.f, 0.f, 0.f);

  const float4* xq = (const float4*)x + (size_t)g * 32 * (Dn / 4) + c;
#pragma unroll 1
  for (int jj = 0; jj < 32; jj += 8) {
    float4 xj[8];
#pragma unroll
    for (int u = 0; u < 8; ++u) xj[u] = xq[(size_t)(jj + u) * (Dn / 4)];
#pragma unroll
    for (int u = 0; u < 8; ++u) {
#pragma unroll
      for (int r = 0; r < 4; ++r) {
        acc[r].x += fabsf(xi[r].x - xj[u].x);
        acc[r].y += fabsf(xi[r].y - xj[u].y);
        acc[r].z += fabsf(xi[r].z - xj[u].z);
        acc[r].w += fabsf(xi[r].w - xj[u].w);
      }
    }
  }
#pragma unroll
  for (int r = 0; r < 4; ++r) *(float4*)&red[g][r][c * 4] = acc[r];
  __syncthreads();

  // ---- Phase 2: reduce 32 j-groups; stage xs, wt_s (verbatim v1) ----
  if (t < 512) {
    const int r = t >> 7, d = t & 127;
    float s = 0.f;
#pragma unroll
    for (int gg = 0; gg < 32; ++gg) s += red[gg][r][d];
    dms[r][d] = s * (1.0f / 1024.0f);
    xs[r][d] = x[(size_t)(i0 + r) * Dn + d];
  } else if (t < 640) {
    wt_s[t - 512] = Wt[t - 512];
  }
  __syncthreads();

  // ---- Phase 3: tau (one wave per row, t<256, verbatim v1) ----
  if (t < 256) {
    const int r = t >> 6, p = t & 63;
    float partial = xs[r][p] * wt_s[p] + xs[r][p + 64] * wt_s[p + 64];
#pragma unroll
    for (int off = 32; off; off >>= 1) partial += __shfl_xor(partial, off, 64);
    if (p == 0) {
      const float z = partial + bt[0];
      const float sp = fmaxf(z, 0.f) + log1pf(expf(-fabsf(z)));  // softplus
      tau_s[r] = 1.0f / (fmaxf(sp, 0.01f) + 1.0f);
    }
  }
  __syncthreads();

  // ---- Phase 4a: ms = (Wd . dm + bd)/tau — full-width, 1024 threads ----
  {
    const int o = t >> 1;       // output index in [0,512)
    const int r = o >> 7;       // row 0..3
    const int h = o & 127;      // output column
    const int half = t & 1;     // k-half: [64*half, 64*half+64)
    const float4* w = (const float4*)(Wd + (size_t)h * Dn) + half * 16;
    const float* dm = &dms[r][half * 64];
    float m = 0.f;
#pragma unroll
    for (int k4 = 0; k4 < 16; ++k4) {
      const float4 wv = w[k4];
      const float4 dv = *(const float4*)(dm + k4 * 4);
      m += wv.x * dv.x + wv.y * dv.y + wv.z * dv.z + wv.w * dv.w;
    }
    m += __shfl_xor(m, 1, 64);  // combine k-halves (pair within wave)
    if (half == 0) ms[r][h] = (m + bd[h]) * tau_s[r];
  }
  __syncthreads();

  // ---- Phase 4b: ys = relu(Wa.m + ba) + Wr.x + br — full-width ----
  {
    const int o = t >> 1;
    const int r = o >> 7;
    const int h = o & 127;
    const int half = t & 1;
    const float4* wa = (const float4*)(Wa + (size_t)h * Dn) + half * 16;
    const float4* wr = (const float4*)(Wr + (size_t)h * Dn) + half * 16;
    const float* mm = &ms[r][half * 64];
    const float* xx = &xs[r][half * 64];
    float q = 0.f, cc = 0.f;
#pragma unroll
    for (int k4 = 0; k4 < 16; ++k4) {
      const float4 av = wa[k4];
      const float4 mv = *(const float4*)(mm + k4 * 4);
      const float4 rv = wr[k4];
      const float4 xv = *(const float4*)(xx + k4 * 4);
      q  += av.x * mv.x + av.y * mv.y + av.z * mv.z + av.w * mv.w;
      cc += rv.x * xv.x + rv.y * xv.y + rv.z * xv.z + rv.w * xv.w;
    }
    q  += __shfl_xor(q, 1, 64);
    cc += __shfl_xor(cc, 1, 64);
    if (half == 0) ys[r][h] = fmaxf(q + ba[h], 0.f) + (cc + br[h]);
  }
  __syncthreads();

  // ---- Phase 5: LayerNorm (one wave per row, t<256, verbatim v1) ----
  if (t < 256) {
    const int r = t >> 6, p = t & 63;
    const float v0 = ys[r][p], v1 = ys[r][p + 64];
    float s = v0 + v1;
    float q = v0 * v0 + v1 * v1;
#pragma unroll
    for (int off = 32; off; off >>= 1) {
      s += __shfl_xor(s, off, 64);
      q += __shfl_xor(q, off, 64);
    }
    const float mu = s * (1.0f / 128.0f);
    const float var = q * (1.0f / 128.0f) - mu * mu;
    const float rs = rsqrtf(var + 1e-5f);
    float* o = out + (size_t)(i0 + r) * Hn;
    o[p]      = (v0 - mu) * rs * gamma[p]      + beta[p];
    o[p + 64] = (v1 - mu) * rs * gamma[p + 64] + beta[p + 64];
  }
}

extern "C" void kernel_launch(void* const* d_in, const int* in_sizes, int n_in,
                              void* d_out, int out_size, void* d_ws,
                              size_t ws_size, hipStream_t stream) {
  const float* x     = (const float*)d_in[0];
  const float* Wd    = (const float*)d_in[1];
  const float* bd    = (const float*)d_in[2];
  const float* Wt    = (const float*)d_in[3];
  const float* bt    = (const float*)d_in[4];
  const float* Wa    = (const float*)d_in[5];
  const float* ba    = (const float*)d_in[6];
  const float* Wr    = (const float*)d_in[7];
  const float* br    = (const float*)d_in[8];
  const float* gamma = (const float*)d_in[9];
  const float* beta  = (const float*)d_in[10];
  float* out = (float*)d_out;

  fused_resd1<<<Bn / 4, 1024, 0, stream>>>(x, Wd, bd, Wt, bt, Wa, ba, Wr, br,
                                           gamma, beta, out);
  (void)in_sizes; (void)n_in; (void)out_size; (void)d_ws; (void)ws_size;
}

// Round 7
// 96.471 us; speedup vs baseline: 1.1111x; 1.1111x over previous
//
#include <hip/hip_runtime.h>
#include <math.h>

// B=1024, D=128, H=128
#define Bn 1024
#define Dn 128
#define Hn 128

// Single fused kernel: 256 blocks x 1024 threads (16 waves/CU, 1 block/CU).
// FINAL = v1, the empirical optimum (94.55 us). Six structural variants all
// regressed or tied:
//   - O(B log B) sort-based dmean (v2/v3): serial 55-step network + block
//     barriers on a half-filled GPU lose to the latency-hidden quadratic.
//   - pre-B1 staging (v4/v5): scratch spill / hot-loop codegen perturbation.
//   - tail-window overlap (v6): neutral — reduce window isn't the long pole.
//   - full-width matvecs (v7): regalloc pressure cut phase 1 to 44 VGPRs,
//     VALUBusy 86->19%, kernel 3x slower.
// Phase 1 needs ~64 VGPRs of live float4 state and 8 loads in flight; any
// edit that shifts whole-kernel regalloc strangles it. Do not touch.
__global__ __launch_bounds__(1024) void fused_resd1(
    const float* __restrict__ x,
    const float* __restrict__ Wd, const float* __restrict__ bd,
    const float* __restrict__ Wt, const float* __restrict__ bt,
    const float* __restrict__ Wa, const float* __restrict__ ba,
    const float* __restrict__ Wr, const float* __restrict__ br,
    const float* __restrict__ gamma, const float* __restrict__ beta,
    float* __restrict__ out) {
  const int t = threadIdx.x;
  const int c = t & 31;   // column quad: cols 4c..4c+3
  const int g = t >> 5;   // j-group in [0,32)
  const int i0 = blockIdx.x << 2;

  __shared__ float red[32][4][Dn];  // 64 KB: per-group partial column sums
  __shared__ float xs[4][Dn];
  __shared__ float dms[4][Dn];
  __shared__ float ms[4][Hn];
  __shared__ float ys[4][Hn];
  __shared__ float wt_s[Dn];
  __shared__ float tau_s[4];        // 1/tau

  // ---- Phase 1: all-pairs partial sums, 8 loads in flight ----
  float4 xi[4];
#pragma unroll
  for (int r = 0; r < 4; ++r)
    xi[r] = *(const float4*)(x + (size_t)(i0 + r) * Dn + c * 4);

  float4 acc[4];
#pragma unroll
  for (int r = 0; r < 4; ++r) acc[r] = make_float4(0.f, 0.f, 0.f, 0.f);

  const float4* xq = (const float4*)x + (size_t)g * 32 * (Dn / 4) + c;
#pragma unroll 1
  for (int jj = 0; jj < 32; jj += 8) {
    float4 xj[8];
#pragma unroll
    for (int u = 0; u < 8; ++u) xj[u] = xq[(size_t)(jj + u) * (Dn / 4)];
#pragma unroll
    for (int u = 0; u < 8; ++u) {
#pragma unroll
      for (int r = 0; r < 4; ++r) {
        acc[r].x += fabsf(xi[r].x - xj[u].x);
        acc[r].y += fabsf(xi[r].y - xj[u].y);
        acc[r].z += fabsf(xi[r].z - xj[u].z);
        acc[r].w += fabsf(xi[r].w - xj[u].w);
      }
    }
  }
#pragma unroll
  for (int r = 0; r < 4; ++r) *(float4*)&red[g][r][c * 4] = acc[r];
  __syncthreads();

  // ---- Phase 2: reduce 32 j-groups -> dms; stage xs, wt_s ----
  if (t < 512) {
    const int r = t >> 7, d = t & 127;
    float s = 0.f;
#pragma unroll
    for (int gg = 0; gg < 32; ++gg) s += red[gg][r][d];
    dms[r][d] = s * (1.0f / 1024.0f);
    xs[r][d] = x[(size_t)(i0 + r) * Dn + d];
  } else if (t < 640) {
    wt_s[t - 512] = Wt[t - 512];
  }
  __syncthreads();

  // ---- Phase 3: tau per row (wave shuffle reduce), t<256 ----
  if (t < 256) {
    const int r = t >> 6, p = t & 63;
    float partial = xs[r][p] * wt_s[p] + xs[r][p + 64] * wt_s[p + 64];
#pragma unroll
    for (int off = 32; off; off >>= 1) partial += __shfl_xor(partial, off, 64);
    if (p == 0) {
      const float z = partial + bt[0];
      const float sp = fmaxf(z, 0.f) + log1pf(expf(-fabsf(z)));  // softplus
      tau_s[r] = 1.0f / (fmaxf(sp, 0.01f) + 1.0f);
    }
  }
  __syncthreads();

  // ---- Phase 4a: m = (Wd . dm + bd) / tau (t<256) ----
  if (t < 256) {
    const int h = t & 127;
    const int g4 = t >> 7;
    const int r0 = 2 * g4, r1 = 2 * g4 + 1;
    float m0 = bd[h], m1 = m0;
    const float4* w = (const float4*)(Wd + (size_t)h * Dn);
#pragma unroll 4
    for (int k4 = 0; k4 < Dn / 4; ++k4) {
      const float4 wv = w[k4];
      const int k = k4 * 4;
      m0 += wv.x * dms[r0][k] + wv.y * dms[r0][k + 1] + wv.z * dms[r0][k + 2] + wv.w * dms[r0][k + 3];
      m1 += wv.x * dms[r1][k] + wv.y * dms[r1][k + 1] + wv.z * dms[r1][k + 2] + wv.w * dms[r1][k + 3];
    }
    ms[r0][h] = m0 * tau_s[r0];
    ms[r1][h] = m1 * tau_s[r1];
  }
  __syncthreads();

  // ---- Phase 4b: y = relu(Wa . m + ba) + Wr . x + br (t<256) ----
  if (t < 256) {
    const int h = t & 127;
    const int g4 = t >> 7;
    const int r0 = 2 * g4, r1 = 2 * g4 + 1;
    float q0 = ba[h], q1 = q0, c0 = br[h], c1 = c0;
    const float4* wa = (const float4*)(Wa + (size_t)h * Dn);
    const float4* wr = (const float4*)(Wr + (size_t)h * Dn);
#pragma unroll 4
    for (int k4 = 0; k4 < Dn / 4; ++k4) {
      const float4 av = wa[k4];
      const float4 rv = wr[k4];
      const int k = k4 * 4;
      q0 += av.x * ms[r0][k] + av.y * ms[r0][k + 1] + av.z * ms[r0][k + 2] + av.w * ms[r0][k + 3];
      q1 += av.x * ms[r1][k] + av.y * ms[r1][k + 1] + av.z * ms[r1][k + 2] + av.w * ms[r1][k + 3];
      c0 += rv.x * xs[r0][k] + rv.y * xs[r0][k + 1] + rv.z * xs[r0][k + 2] + rv.w * xs[r0][k + 3];
      c1 += rv.x * xs[r1][k] + rv.y * xs[r1][k + 1] + rv.z * xs[r1][k + 2] + rv.w * xs[r1][k + 3];
    }
    ys[r0][h] = fmaxf(q0, 0.f) + c0;
    ys[r1][h] = fmaxf(q1, 0.f) + c1;
  }
  __syncthreads();

  // ---- Phase 5: LayerNorm per row (t<256) ----
  if (t < 256) {
    const int r = t >> 6, p = t & 63;
    const float v0 = ys[r][p], v1 = ys[r][p + 64];
    float s = v0 + v1;
    float q = v0 * v0 + v1 * v1;
#pragma unroll
    for (int off = 32; off; off >>= 1) {
      s += __shfl_xor(s, off, 64);
      q += __shfl_xor(q, off, 64);
    }
    const float mu = s * (1.0f / 128.0f);
    const float var = q * (1.0f / 128.0f) - mu * mu;
    const float rs = rsqrtf(var + 1e-5f);
    float* o = out + (size_t)(i0 + r) * Hn;
    o[p]      = (v0 - mu) * rs * gamma[p]      + beta[p];
    o[p + 64] = (v1 - mu) * rs * gamma[p + 64] + beta[p + 64];
  }
}

extern "C" void kernel_launch(void* const* d_in, const int* in_sizes, int n_in,
                              void* d_out, int out_size, void* d_ws, size_t ws_size,
                              hipStream_t stream) {
  const float* x     = (const float*)d_in[0];
  const float* Wd    = (const float*)d_in[1];
  const float* bd    = (const float*)d_in[2];
  const float* Wt    = (const float*)d_in[3];
  const float* bt    = (const float*)d_in[4];
  const float* Wa    = (const float*)d_in[5];
  const float* ba    = (const float*)d_in[6];
  const float* Wr    = (const float*)d_in[7];
  const float* br    = (const float*)d_in[8];
  const float* gamma = (const float*)d_in[9];
  const float* beta  = (const float*)d_in[10];
  float* out = (float*)d_out;

  fused_resd1<<<Bn / 4, 1024, 0, stream>>>(x, Wd, bd, Wt, bt, Wa, ba, Wr, br,
                                           gamma, beta, out);
  (void)in_sizes; (void)n_in; (void)out_size; (void)d_ws; (void)ws_size;
}